// Round 1
// baseline (1652.388 us; speedup 1.0000x reference)
//
#include <hip/hip_runtime.h>
#include <stdint.h>

typedef unsigned short u16;
typedef __attribute__((ext_vector_type(4))) float f32x4;
typedef __attribute__((ext_vector_type(8))) __bf16 bf16x8;
typedef __attribute__((ext_vector_type(8))) unsigned short u16x8;

__device__ __forceinline__ u16 f2bf(float f) {
  unsigned u = __builtin_bit_cast(unsigned, f);
  u = (u + 0x7fffu + ((u >> 16) & 1u)) >> 16;
  return (u16)u;
}

typedef __attribute__((address_space(1))) const void gvoid_t;
typedef __attribute__((address_space(3))) void lvoid_t;

__device__ __forceinline__ void gload_lds16(const void* g, void* l) {
  __builtin_amdgcn_global_load_lds((gvoid_t*)g, (lvoid_t*)l, 16, 0, 0);
}

// ---------------- dequant: w[row][k] = (q[row][k] - z[row][k/128]) * s[row][k/128], bf16
// grid: (K/8/256, O), block 256. Each thread: 8 contiguous elems (one group only).
__global__ __launch_bounds__(256)
void dequant_kernel(const int* __restrict__ q, const float* __restrict__ s,
                    const int* __restrict__ z, u16* __restrict__ w, int K) {
  const int row = blockIdx.y;
  const int k = (blockIdx.x * 256 + threadIdx.x) << 3;
  const int ng = K >> 7;
  const int g = k >> 7;
  const float sv = s[(size_t)row * ng + g];
  const float zv = (float)z[(size_t)row * ng + g];
  const int4* qp = (const int4*)(q + (size_t)row * K + k);
  const int4 a = qp[0], b = qp[1];
  u16x8 o;
  o[0] = f2bf(((float)a.x - zv) * sv);
  o[1] = f2bf(((float)a.y - zv) * sv);
  o[2] = f2bf(((float)a.z - zv) * sv);
  o[3] = f2bf(((float)a.w - zv) * sv);
  o[4] = f2bf(((float)b.x - zv) * sv);
  o[5] = f2bf(((float)b.y - zv) * sv);
  o[6] = f2bf(((float)b.z - zv) * sv);
  o[7] = f2bf(((float)b.w - zv) * sv);
  *reinterpret_cast<u16x8*>(w + (size_t)row * K + k) = o;
}

// ---------------- GEMM: C[M,N] = A[M,K] * B[N,K]^T  (B^T layout, K-major both)
// 128x128 tile, BK=64, 4 waves (2x2), 16x16x32 bf16 MFMA, 4x4 frags/wave.
// A_IS_F32: A is fp32, reg-staged with fused cvt to bf16. Else bf16 via global_load_lds.
// RELU2_OUT: C = bf16(relu(acc)^2). Else C = fp32 acc.
template<bool A_IS_F32, bool RELU2_OUT>
__global__ __launch_bounds__(256)
void gemm_kernel(const void* __restrict__ Aptr, const u16* __restrict__ B,
                 void* __restrict__ Cptr, int M, int N, int K) {
  __shared__ __align__(16) u16 As[128][64];
  __shared__ __align__(16) u16 Bs[128][64];
  const int tid = threadIdx.x;
  const int lane = tid & 63;
  const int wid = tid >> 6;
  const int wr = wid >> 1, wc = wid & 1;
  const int m0 = blockIdx.y * 128;
  const int n0 = blockIdx.x * 128;
  const int lr = lane & 15;          // fragment row within 16 (A: m, B: n)
  const int lk = (lane >> 4) << 3;   // fragment k base (0,8,16,24)

  f32x4 acc[4][4] = {};

  const int nk = K >> 6;
  for (int kt = 0; kt < nk; ++kt) {
    const int k0 = kt << 6;
    // stage B: 128x64 bf16 = 16KB, 4 x 16B chunks per thread, linear LDS order
#pragma unroll
    for (int i = 0; i < 4; ++i) {
      const int qq = tid + i * 256;
      const int r = qq >> 3, c = (qq & 7) << 3;
      gload_lds16(B + (size_t)(n0 + r) * K + (k0 + c), &Bs[r][c]);
    }
    if constexpr (A_IS_F32) {
      const float* Af = (const float*)Aptr;
#pragma unroll
      for (int i = 0; i < 4; ++i) {
        const int qq = tid + i * 256;
        const int r = qq >> 3, c = (qq & 7) << 3;
        const float4* src = (const float4*)(Af + (size_t)(m0 + r) * K + (k0 + c));
        const float4 f0 = src[0], f1 = src[1];
        u16x8 o;
        o[0] = f2bf(f0.x); o[1] = f2bf(f0.y); o[2] = f2bf(f0.z); o[3] = f2bf(f0.w);
        o[4] = f2bf(f1.x); o[5] = f2bf(f1.y); o[6] = f2bf(f1.z); o[7] = f2bf(f1.w);
        *reinterpret_cast<u16x8*>(&As[r][c]) = o;
      }
    } else {
      const u16* Ab = (const u16*)Aptr;
#pragma unroll
      for (int i = 0; i < 4; ++i) {
        const int qq = tid + i * 256;
        const int r = qq >> 3, c = (qq & 7) << 3;
        gload_lds16(Ab + (size_t)(m0 + r) * K + (k0 + c), &As[r][c]);
      }
    }
    __syncthreads();  // compiler drains vmcnt+lgkmcnt before s_barrier
#pragma unroll
    for (int ks = 0; ks < 2; ++ks) {
      bf16x8 af[4], bfr[4];
#pragma unroll
      for (int i = 0; i < 4; ++i)
        af[i] = *reinterpret_cast<const bf16x8*>(&As[wr * 64 + i * 16 + lr][ks * 32 + lk]);
#pragma unroll
      for (int j = 0; j < 4; ++j)
        bfr[j] = *reinterpret_cast<const bf16x8*>(&Bs[wc * 64 + j * 16 + lr][ks * 32 + lk]);
#pragma unroll
      for (int i = 0; i < 4; ++i)
#pragma unroll
        for (int j = 0; j < 4; ++j)
          acc[i][j] = __builtin_amdgcn_mfma_f32_16x16x32_bf16(af[i], bfr[j], acc[i][j], 0, 0, 0);
    }
    __syncthreads();
  }
  // epilogue: C/D layout col = lane&15, row = (lane>>4)*4 + reg  [m89-verified]
  const int crow = (lane >> 4) << 2;
  const int ccol = lane & 15;
#pragma unroll
  for (int i = 0; i < 4; ++i) {
#pragma unroll
    for (int j = 0; j < 4; ++j) {
#pragma unroll
      for (int qq = 0; qq < 4; ++qq) {
        const int m = m0 + wr * 64 + i * 16 + crow + qq;
        const int n = n0 + wc * 64 + j * 16 + ccol;
        const float v = acc[i][j][qq];
        if constexpr (RELU2_OUT) {
          const float r = fmaxf(v, 0.f);
          ((u16*)Cptr)[(size_t)m * N + n] = f2bf(r * r);
        } else {
          ((float*)Cptr)[(size_t)m * N + n] = v;
        }
      }
    }
  }
}

extern "C" void kernel_launch(void* const* d_in, const int* in_sizes, int n_in,
                              void* d_out, int out_size, void* d_ws, size_t ws_size,
                              hipStream_t stream) {
  const float* x    = (const float*)d_in[0];
  const int*   q_up = (const int*)d_in[1];
  const float* s_up = (const float*)d_in[2];
  const int*   z_up = (const int*)d_in[3];
  const int*   q_dn = (const int*)d_in[4];
  const float* s_dn = (const float*)d_in[5];
  const int*   z_dn = (const int*)d_in[6];
  float* y = (float*)d_out;

  const int H = 4096, I = 14336;
  const int M = in_sizes[0] / H;  // 4096 tokens

  const size_t wbytes = (size_t)I * H * 2;  // 117,440,512 B (bf16 weight buffer)
  u16* wbuf = (u16*)d_ws;                      // reused for W_up then W_down
  u16* abuf = (u16*)((char*)d_ws + wbytes);    // a = relu2(h), bf16 [M, I]
  if (ws_size < 2 * wbytes) return;  // insufficient scratch: fail cleanly

  // 1. dequant W_up [I, H] -> bf16
  dequant_kernel<<<dim3(H / 8 / 256, I), 256, 0, stream>>>(q_up, s_up, z_up, wbuf, H);
  // 2. a = relu(x @ W_up^T)^2, bf16
  gemm_kernel<true, true><<<dim3(I / 128, M / 128), 256, 0, stream>>>(x, wbuf, abuf, M, I, H);
  // 3. dequant W_down [H, I] -> bf16 (overwrites wbuf; stream-ordered after GEMM1)
  dequant_kernel<<<dim3(I / 8 / 256, H), 256, 0, stream>>>(q_dn, s_dn, z_dn, wbuf, I);
  // 4. y = a @ W_down^T, fp32
  gemm_kernel<false, false><<<dim3(H / 128, M / 128), 256, 0, stream>>>(abuf, wbuf, y, M, H, I);
}

// Round 2
// 1242.274 us; speedup vs baseline: 1.3301x; 1.3301x over previous
//
#include <hip/hip_runtime.h>
#include <stdint.h>

typedef unsigned short u16;
typedef __attribute__((ext_vector_type(4))) float f32x4;
typedef __attribute__((ext_vector_type(8))) __bf16 bf16x8;
typedef __attribute__((ext_vector_type(8))) unsigned short u16x8;

__device__ __forceinline__ u16 f2bf(float f) {
  unsigned u = __builtin_bit_cast(unsigned, f);
  u = (u + 0x7fffu + ((u >> 16) & 1u)) >> 16;
  return (u16)u;
}

typedef __attribute__((address_space(1))) const void gvoid_t;
typedef __attribute__((address_space(3))) void lvoid_t;

__device__ __forceinline__ void gload_lds16(const void* g, void* l) {
  __builtin_amdgcn_global_load_lds((gvoid_t*)g, (lvoid_t*)l, 16, 0, 0);
}

// ---------------- dequant: w[row][k] = (q[row][k] - z[row][k/128]) * s[row][k/128], bf16
__global__ __launch_bounds__(256)
void dequant_kernel(const int* __restrict__ q, const float* __restrict__ s,
                    const int* __restrict__ z, u16* __restrict__ w, int K) {
  const int row = blockIdx.y;
  const int k = (blockIdx.x * 256 + threadIdx.x) << 3;
  const int ng = K >> 7;
  const int g = k >> 7;
  const float sv = s[(size_t)row * ng + g];
  const float zv = (float)z[(size_t)row * ng + g];
  const int4* qp = (const int4*)(q + (size_t)row * K + k);
  const int4 a = qp[0], b = qp[1];
  u16x8 o;
  o[0] = f2bf(((float)a.x - zv) * sv);
  o[1] = f2bf(((float)a.y - zv) * sv);
  o[2] = f2bf(((float)a.z - zv) * sv);
  o[3] = f2bf(((float)a.w - zv) * sv);
  o[4] = f2bf(((float)b.x - zv) * sv);
  o[5] = f2bf(((float)b.y - zv) * sv);
  o[6] = f2bf(((float)b.z - zv) * sv);
  o[7] = f2bf(((float)b.w - zv) * sv);
  *reinterpret_cast<u16x8*>(w + (size_t)row * K + k) = o;
}

// ---------------- fp32 -> bf16 bulk convert (x)
__global__ __launch_bounds__(256)
void cvt_kernel(const float* __restrict__ in, u16* __restrict__ out) {
  const size_t i = ((size_t)blockIdx.x * 256 + threadIdx.x) << 3;
  const float4* p = (const float4*)(in + i);
  const float4 a = p[0], b = p[1];
  u16x8 o;
  o[0] = f2bf(a.x); o[1] = f2bf(a.y); o[2] = f2bf(a.z); o[3] = f2bf(a.w);
  o[4] = f2bf(b.x); o[5] = f2bf(b.y); o[6] = f2bf(b.z); o[7] = f2bf(b.w);
  *reinterpret_cast<u16x8*>(out + i) = o;
}

// ---------------- GEMM: C[M,N] = A[M,K] * B[N,K]^T  (both K-major)
// 128x128 tile, BK=64, 4 waves (2x2), 16x16x32 bf16 MFMA, 4x4 frags/wave.
// LDS XOR-swizzle (T2): logical (row,col) lives at LDS[row][col ^ ((row&7)<<3)].
// gload_lds dest stays LINEAR; global source col is inverse-swizzled (involution).
// A_IS_F32: A fp32, reg-staged + cvt + swizzled ds_write. RELU2_OUT: C=bf16(relu(acc)^2).
template<bool A_IS_F32, bool RELU2_OUT>
__global__ __launch_bounds__(256)
void gemm_kernel(const void* __restrict__ Aptr, const u16* __restrict__ B,
                 void* __restrict__ Cptr, int M, int N, int K) {
  __shared__ __align__(16) u16 As[128][64];
  __shared__ __align__(16) u16 Bs[128][64];
  const int tid = threadIdx.x;
  const int lane = tid & 63;
  const int wid = tid >> 6;
  const int wr = wid >> 1, wc = wid & 1;
  const int m0 = blockIdx.y * 128;
  const int n0 = blockIdx.x * 128;
  const int lr = lane & 15;          // fragment row within 16
  const int lk = (lane >> 4) << 3;   // fragment k base (0,8,16,24)

  f32x4 acc[4][4] = {};

  const int nk = K >> 6;
  for (int kt = 0; kt < nk; ++kt) {
    const int k0 = kt << 6;
    // stage B: 128x64 bf16; LDS dest linear, global col inverse-swizzled
#pragma unroll
    for (int i = 0; i < 4; ++i) {
      const int qq = tid + i * 256;
      const int r = qq >> 3;
      const int cl = (qq & 7) << 3;                       // linear LDS col
      const int cs = (((qq & 7) ^ (r & 7)) << 3);         // swizzled global col
      gload_lds16(B + (size_t)(n0 + r) * K + (k0 + cs), &Bs[r][cl]);
    }
    if constexpr (A_IS_F32) {
      const float* Af = (const float*)Aptr;
#pragma unroll
      for (int i = 0; i < 4; ++i) {
        const int qq = tid + i * 256;
        const int r = qq >> 3, c = (qq & 7) << 3;
        const float4* src = (const float4*)(Af + (size_t)(m0 + r) * K + (k0 + c));
        const float4 f0 = src[0], f1 = src[1];
        u16x8 o;
        o[0] = f2bf(f0.x); o[1] = f2bf(f0.y); o[2] = f2bf(f0.z); o[3] = f2bf(f0.w);
        o[4] = f2bf(f1.x); o[5] = f2bf(f1.y); o[6] = f2bf(f1.z); o[7] = f2bf(f1.w);
        *reinterpret_cast<u16x8*>(&As[r][c ^ ((r & 7) << 3)]) = o;  // swizzled write
      }
    } else {
      const u16* Ab = (const u16*)Aptr;
#pragma unroll
      for (int i = 0; i < 4; ++i) {
        const int qq = tid + i * 256;
        const int r = qq >> 3;
        const int cl = (qq & 7) << 3;
        const int cs = (((qq & 7) ^ (r & 7)) << 3);
        gload_lds16(Ab + (size_t)(m0 + r) * K + (k0 + cs), &As[r][cl]);
      }
    }
    __syncthreads();
#pragma unroll
    for (int ks = 0; ks < 2; ++ks) {
      bf16x8 af[4], bfr[4];
#pragma unroll
      for (int i = 0; i < 4; ++i) {
        const int row = wr * 64 + i * 16 + lr;
        af[i] = *reinterpret_cast<const bf16x8*>(&As[row][(ks * 32 + lk) ^ ((row & 7) << 3)]);
      }
#pragma unroll
      for (int j = 0; j < 4; ++j) {
        const int row = wc * 64 + j * 16 + lr;
        bfr[j] = *reinterpret_cast<const bf16x8*>(&Bs[row][(ks * 32 + lk) ^ ((row & 7) << 3)]);
      }
#pragma unroll
      for (int i = 0; i < 4; ++i)
#pragma unroll
        for (int j = 0; j < 4; ++j)
          acc[i][j] = __builtin_amdgcn_mfma_f32_16x16x32_bf16(af[i], bfr[j], acc[i][j], 0, 0, 0);
    }
    __syncthreads();
  }
  // epilogue: C/D layout col = lane&15, row = (lane>>4)*4 + reg  [m89-verified]
  const int crow = (lane >> 4) << 2;
  const int ccol = lane & 15;
#pragma unroll
  for (int i = 0; i < 4; ++i) {
#pragma unroll
    for (int j = 0; j < 4; ++j) {
#pragma unroll
      for (int qq = 0; qq < 4; ++qq) {
        const int m = m0 + wr * 64 + i * 16 + crow + qq;
        const int n = n0 + wc * 64 + j * 16 + ccol;
        const float v = acc[i][j][qq];
        if constexpr (RELU2_OUT) {
          const float r = fmaxf(v, 0.f);
          ((u16*)Cptr)[(size_t)m * N + n] = f2bf(r * r);
        } else {
          ((float*)Cptr)[(size_t)m * N + n] = v;
        }
      }
    }
  }
}

extern "C" void kernel_launch(void* const* d_in, const int* in_sizes, int n_in,
                              void* d_out, int out_size, void* d_ws, size_t ws_size,
                              hipStream_t stream) {
  const float* x    = (const float*)d_in[0];
  const int*   q_up = (const int*)d_in[1];
  const float* s_up = (const float*)d_in[2];
  const int*   z_up = (const int*)d_in[3];
  const int*   q_dn = (const int*)d_in[4];
  const float* s_dn = (const float*)d_in[5];
  const int*   z_dn = (const int*)d_in[6];
  float* y = (float*)d_out;

  const int H = 4096, I = 14336;
  const int M = in_sizes[0] / H;  // 4096 tokens

  const size_t wbytes = (size_t)I * H * 2;   // 117.4 MB bf16 weight buffer (reused)
  const size_t abytes = (size_t)M * I * 2;   // 117.4 MB bf16 activations
  const size_t xbytes = (size_t)M * H * 2;   // 33.5 MB bf16 x
  u16* wbuf = (u16*)d_ws;
  u16* abuf = (u16*)((char*)d_ws + wbytes);
  u16* xbf  = (u16*)((char*)d_ws + wbytes + abytes);
  if (ws_size < wbytes + abytes) return;  // insufficient scratch: fail cleanly
  const bool have_x = ws_size >= wbytes + abytes + xbytes;

  // 1. dequant W_up [I, H] -> bf16
  dequant_kernel<<<dim3(H / 8 / 256, I), 256, 0, stream>>>(q_up, s_up, z_up, wbuf, H);
  if (have_x) {
    // 1b. x -> bf16
    cvt_kernel<<<dim3((int)(((size_t)M * H) >> 11)), 256, 0, stream>>>(x, xbf);
    // 2. a = relu(x @ W_up^T)^2, bf16
    gemm_kernel<false, true><<<dim3(I / 128, M / 128), 256, 0, stream>>>(xbf, wbuf, abuf, M, I, H);
  } else {
    gemm_kernel<true, true><<<dim3(I / 128, M / 128), 256, 0, stream>>>(x, wbuf, abuf, M, I, H);
  }
  // 3. dequant W_down [H, I] -> bf16
  dequant_kernel<<<dim3(I / 8 / 256, H), 256, 0, stream>>>(q_dn, s_dn, z_dn, wbuf, I);
  // 4. y = a @ W_down^T, fp32
  gemm_kernel<false, false><<<dim3(H / 128, M / 128), 256, 0, stream>>>(abuf, wbuf, y, M, H, I);
}

// Round 3
// 1093.720 us; speedup vs baseline: 1.5108x; 1.1358x over previous
//
#include <hip/hip_runtime.h>
#include <stdint.h>

typedef unsigned short u16;
typedef __attribute__((ext_vector_type(4))) float f32x4;
typedef __attribute__((ext_vector_type(8))) __bf16 bf16x8;
typedef __attribute__((ext_vector_type(8))) unsigned short u16x8;

__device__ __forceinline__ u16 f2bf(float f) {
  unsigned u = __builtin_bit_cast(unsigned, f);
  u = (u + 0x7fffu + ((u >> 16) & 1u)) >> 16;
  return (u16)u;
}

typedef __attribute__((address_space(1))) const void gvoid_t;
typedef __attribute__((address_space(3))) void lvoid_t;

__device__ __forceinline__ void gload_lds16(const void* g, void* l) {
  __builtin_amdgcn_global_load_lds((gvoid_t*)g, (lvoid_t*)l, 16, 0, 0);
}

// ---------------- dequant: w[row][k] = (q[row][k] - z[row][k/128]) * s[row][k/128], bf16
__global__ __launch_bounds__(256)
void dequant_kernel(const int* __restrict__ q, const float* __restrict__ s,
                    const int* __restrict__ z, u16* __restrict__ w, int K) {
  const int row = blockIdx.y;
  const int k = (blockIdx.x * 256 + threadIdx.x) << 3;
  const int ng = K >> 7;
  const int g = k >> 7;
  const float sv = s[(size_t)row * ng + g];
  const float zv = (float)z[(size_t)row * ng + g];
  const int4* qp = (const int4*)(q + (size_t)row * K + k);
  const int4 a = qp[0], b = qp[1];
  u16x8 o;
  o[0] = f2bf(((float)a.x - zv) * sv);
  o[1] = f2bf(((float)a.y - zv) * sv);
  o[2] = f2bf(((float)a.z - zv) * sv);
  o[3] = f2bf(((float)a.w - zv) * sv);
  o[4] = f2bf(((float)b.x - zv) * sv);
  o[5] = f2bf(((float)b.y - zv) * sv);
  o[6] = f2bf(((float)b.z - zv) * sv);
  o[7] = f2bf(((float)b.w - zv) * sv);
  *reinterpret_cast<u16x8*>(w + (size_t)row * K + k) = o;
}

// ---------------- fp32 -> bf16 bulk convert (x)
__global__ __launch_bounds__(256)
void cvt_kernel(const float* __restrict__ in, u16* __restrict__ out) {
  const size_t i = ((size_t)blockIdx.x * 256 + threadIdx.x) << 3;
  const float4* p = (const float4*)(in + i);
  const float4 a = p[0], b = p[1];
  u16x8 o;
  o[0] = f2bf(a.x); o[1] = f2bf(a.y); o[2] = f2bf(a.z); o[3] = f2bf(a.w);
  o[4] = f2bf(b.x); o[5] = f2bf(b.y); o[6] = f2bf(b.z); o[7] = f2bf(b.w);
  *reinterpret_cast<u16x8*>(out + i) = o;
}

// ---------------- 256x256 8-phase GEMM: C[M,N] = A[M,K] * B[N,K]^T (bf16, K-major)
// 512 thr = 8 waves (2M x 4N); per-wave 128x64 out; BK=64; buf0=even K-tiles, buf1=odd.
// Phase schedule (ledger-verified):
//   ph1: rd af i0-3 + bfr j0-1 (buf0) | stg B[T1]h0 -> buf1.B | MFMA acc[0-3][0-1]
//   ph2: rd af i4-7                    | stg B[T1]h1           | MFMA acc[4-7][0-1]
//   ph3: rd bfr j2-3                   | stg A[T0+2]h0 -> buf0.A| MFMA acc[4-7][2-3]
//   ph4: (no reads)                    | stg A[T0+2]h1         | MFMA acc[0-3][2-3]; vmcnt(4)
//   ph5-8: same on buf1; stg B[T0+2]h0/h1 -> buf0.B, A[T1+2]h0/h1 -> buf1.A; vmcnt(4) @ph8
// Region-free: buf0.A freed by ph2-end barrier, buf0.B by ph3, buf1.A by ph6, buf1.B by ph7.
// Landing: ph4's vmcnt(4) leaves only {ph3,ph4} in flight -> T1 complete before ph5;
//          ph8's vmcnt(4) leaves {ph7,ph8} -> T0+2 complete before next ph1.
template<bool RELU2>
__global__ __launch_bounds__(512, 2)
void gemm256(const u16* __restrict__ Ap, const u16* __restrict__ Bp,
             void* __restrict__ Cptr, int M, int N, int K) {
  __shared__ __align__(16) u16 As[2][256][64];
  __shared__ __align__(16) u16 Bs[2][256][64];
  const int tid = threadIdx.x;
  const int lane = tid & 63;
  const int wid = tid >> 6;
  const int wr = wid >> 2, wc = wid & 3;

  const int nbx = N >> 8;
  const int nwg = gridDim.x;
  int bid = blockIdx.x;
  bid = (bid & 7) * (nwg >> 3) + (bid >> 3);   // XCD swizzle (nwg % 8 == 0)
  const int m0 = (bid / nbx) << 8;
  const int n0 = (bid % nbx) << 8;

  const int srow = tid >> 3;        // staging row within 64-row sweep
  const int scol = tid & 7;         // staging 16B segment
  const int lr = lane & 15;
  const int lk = (lane >> 4) << 3;
  const int xorc = (lr & 7) << 3;   // read-side swizzle (row&7 == lr&7)

  f32x4 acc[8][4] = {};
  bf16x8 af[8][2], bfr[4][2];

  const int nk = K >> 6;

#define STG_A(bufi, h, kt) do { _Pragma("unroll") \
  for (int l_ = 0; l_ < 2; ++l_) { \
    const int r_ = (h) * 128 + l_ * 64 + srow; \
    gload_lds16(Ap + (size_t)(m0 + r_) * K + (size_t)((kt) << 6) + ((scol ^ (srow & 7)) << 3), \
                &As[bufi][r_][scol << 3]); } } while (0)
#define STG_B(bufi, h, kt) do { _Pragma("unroll") \
  for (int l_ = 0; l_ < 2; ++l_) { \
    const int r_ = (h) * 128 + l_ * 64 + srow; \
    gload_lds16(Bp + (size_t)(n0 + r_) * K + (size_t)((kt) << 6) + ((scol ^ (srow & 7)) << 3), \
                &Bs[bufi][r_][scol << 3]); } } while (0)
#define LD_AF(bufi, i0) do { _Pragma("unroll") \
  for (int i_ = 0; i_ < 4; ++i_) { _Pragma("unroll") \
    for (int ks_ = 0; ks_ < 2; ++ks_) \
      af[(i0) + i_][ks_] = *reinterpret_cast<const bf16x8*>( \
        &As[bufi][wr * 128 + ((i0) + i_) * 16 + lr][(ks_ * 32 + lk) ^ xorc]); } } while (0)
#define LD_BF(bufi, j0) do { _Pragma("unroll") \
  for (int j_ = 0; j_ < 2; ++j_) { _Pragma("unroll") \
    for (int ks_ = 0; ks_ < 2; ++ks_) \
      bfr[(j0) + j_][ks_] = *reinterpret_cast<const bf16x8*>( \
        &Bs[bufi][wc * 64 + ((j0) + j_) * 16 + lr][(ks_ * 32 + lk) ^ xorc]); } } while (0)
#define MFMA_Q(I0, J0) do { _Pragma("unroll") \
  for (int ks_ = 0; ks_ < 2; ++ks_) { _Pragma("unroll") \
    for (int i_ = 0; i_ < 4; ++i_) { _Pragma("unroll") \
      for (int j_ = 0; j_ < 2; ++j_) \
        acc[(I0) + i_][(J0) + j_] = __builtin_amdgcn_mfma_f32_16x16x32_bf16( \
          af[(I0) + i_][ks_], bfr[(J0) + j_][ks_], acc[(I0) + i_][(J0) + j_], 0, 0, 0); } } } while (0)
#define BARRIER() do { asm volatile("" ::: "memory"); __builtin_amdgcn_s_barrier(); \
  asm volatile("" ::: "memory"); } while (0)
#define PH_TAIL(Q) do { BARRIER(); \
  asm volatile("s_waitcnt lgkmcnt(0)" ::: "memory"); \
  __builtin_amdgcn_s_setprio(1); Q; __builtin_amdgcn_s_setprio(0); \
  BARRIER(); } while (0)
#define PH_TAIL_VM(Q) do { BARRIER(); \
  asm volatile("s_waitcnt lgkmcnt(0)" ::: "memory"); \
  __builtin_amdgcn_s_setprio(1); Q; __builtin_amdgcn_s_setprio(0); \
  asm volatile("s_waitcnt vmcnt(4)" ::: "memory"); \
  BARRIER(); } while (0)

  // prologue: A[0]->buf0.A, B[0]->buf0.B, A[1]->buf1.A; allow A[1] (4 loads) in flight
  STG_A(0, 0, 0); STG_A(0, 1, 0);
  STG_B(0, 0, 0); STG_B(0, 1, 0);
  STG_A(1, 0, 1); STG_A(1, 1, 1);
  asm volatile("s_waitcnt vmcnt(4)" ::: "memory");
  BARRIER();

  const int nit = nk >> 1;
  for (int it = 0; it < nit; ++it) {
    const int t1 = it * 2 + 1;
    int ta2 = it * 2 + 2; if (ta2 >= nk) ta2 -= nk;   // wrap: tail stages are dummies
    int ta3 = it * 2 + 3; if (ta3 >= nk) ta3 -= nk;
    // ph1
    LD_AF(0, 0); LD_BF(0, 0);
    STG_B(1, 0, t1);
    PH_TAIL(MFMA_Q(0, 0));
    // ph2
    LD_AF(0, 4);
    STG_B(1, 1, t1);
    PH_TAIL(MFMA_Q(4, 0));
    // ph3
    LD_BF(0, 2);
    STG_A(0, 0, ta2);
    PH_TAIL(MFMA_Q(4, 2));
    // ph4
    STG_A(0, 1, ta2);
    PH_TAIL_VM(MFMA_Q(0, 2));
    // ph5
    LD_AF(1, 0); LD_BF(1, 0);
    STG_B(0, 0, ta2);
    PH_TAIL(MFMA_Q(0, 0));
    // ph6
    LD_AF(1, 4);
    STG_B(0, 1, ta2);
    PH_TAIL(MFMA_Q(4, 0));
    // ph7
    LD_BF(1, 2);
    STG_A(1, 0, ta3);
    PH_TAIL(MFMA_Q(4, 2));
    // ph8
    STG_A(1, 1, ta3);
    PH_TAIL_VM(MFMA_Q(0, 2));
  }
  asm volatile("s_waitcnt vmcnt(0)" ::: "memory");  // drain dummy stages before endpgm

  // epilogue: C/D layout col = lane&15, row = (lane>>4)*4 + reg  [m89-verified]
  const int crow = (lane >> 4) << 2;
  const int ccol = lane & 15;
#pragma unroll
  for (int i = 0; i < 8; ++i) {
#pragma unroll
    for (int j = 0; j < 4; ++j) {
#pragma unroll
      for (int q = 0; q < 4; ++q) {
        const int m = m0 + wr * 128 + i * 16 + crow + q;
        const int n = n0 + wc * 64 + j * 16 + ccol;
        const float v = acc[i][j][q];
        if constexpr (RELU2) {
          const float r = fmaxf(v, 0.f);
          ((u16*)Cptr)[(size_t)m * N + n] = f2bf(r * r);
        } else {
          ((float*)Cptr)[(size_t)m * N + n] = v;
        }
      }
    }
  }
#undef STG_A
#undef STG_B
#undef LD_AF
#undef LD_BF
#undef MFMA_Q
#undef BARRIER
#undef PH_TAIL
#undef PH_TAIL_VM
}

extern "C" void kernel_launch(void* const* d_in, const int* in_sizes, int n_in,
                              void* d_out, int out_size, void* d_ws, size_t ws_size,
                              hipStream_t stream) {
  const float* x    = (const float*)d_in[0];
  const int*   q_up = (const int*)d_in[1];
  const float* s_up = (const float*)d_in[2];
  const int*   z_up = (const int*)d_in[3];
  const int*   q_dn = (const int*)d_in[4];
  const float* s_dn = (const float*)d_in[5];
  const int*   z_dn = (const int*)d_in[6];
  float* y = (float*)d_out;

  const int H = 4096, I = 14336;
  const int M = in_sizes[0] / H;  // 4096 tokens

  const size_t wbytes = (size_t)I * H * 2;   // 117.4 MB bf16 weight buffer (reused)
  const size_t abytes = (size_t)M * I * 2;   // 117.4 MB bf16 activations
  const size_t xbytes = (size_t)M * H * 2;   // 33.5 MB bf16 x
  u16* wbuf = (u16*)d_ws;
  u16* abuf = (u16*)((char*)d_ws + wbytes);
  u16* xbf  = (u16*)((char*)d_ws + wbytes + abytes);
  if (ws_size < wbytes + abytes + xbytes) return;  // insufficient scratch: fail cleanly

  // 1. dequant W_up [I, H] -> bf16
  dequant_kernel<<<dim3(H / 8 / 256, I), 256, 0, stream>>>(q_up, s_up, z_up, wbuf, H);
  // 1b. x -> bf16
  cvt_kernel<<<dim3((int)(((size_t)M * H) >> 11)), 256, 0, stream>>>(x, xbf);
  // 2. a = relu(x @ W_up^T)^2, bf16   (grid 896 % 8 == 0)
  gemm256<true><<<dim3((M / 256) * (I / 256)), 512, 0, stream>>>(xbf, wbuf, abuf, M, I, H);
  // 3. dequant W_down [H, I] -> bf16
  dequant_kernel<<<dim3(I / 8 / 256, H), 256, 0, stream>>>(q_dn, s_dn, z_dn, wbuf, I);
  // 4. y = a @ W_down^T, fp32   (grid 256 % 8 == 0)
  gemm256<false><<<dim3((M / 256) * (H / 256)), 512, 0, stream>>>(abuf, wbuf, y, M, H, I);
}

// Round 4
// 1068.450 us; speedup vs baseline: 1.5465x; 1.0237x over previous
//
#include <hip/hip_runtime.h>
#include <stdint.h>

typedef unsigned short u16;
typedef __attribute__((ext_vector_type(4))) float f32x4;
typedef __attribute__((ext_vector_type(8))) __bf16 bf16x8;
typedef __attribute__((ext_vector_type(8))) unsigned short u16x8;

__device__ __forceinline__ u16 f2bf(float f) {
  unsigned u = __builtin_bit_cast(unsigned, f);
  u = (u + 0x7fffu + ((u >> 16) & 1u)) >> 16;
  return (u16)u;
}

typedef __attribute__((address_space(1))) const void gvoid_t;
typedef __attribute__((address_space(3))) void lvoid_t;

__device__ __forceinline__ void gload_lds16(const void* g, void* l) {
  __builtin_amdgcn_global_load_lds((gvoid_t*)g, (lvoid_t*)l, 16, 0, 0);
}

// ---------------- dequant: w[row][k] = (q[row][k] - z[row][k/128]) * s[row][k/128], bf16
__global__ __launch_bounds__(256)
void dequant_kernel(const int* __restrict__ q, const float* __restrict__ s,
                    const int* __restrict__ z, u16* __restrict__ w, int K) {
  const int row = blockIdx.y;
  const int k = (blockIdx.x * 256 + threadIdx.x) << 3;
  const int ng = K >> 7;
  const int g = k >> 7;
  const float sv = s[(size_t)row * ng + g];
  const float zv = (float)z[(size_t)row * ng + g];
  const int4* qp = (const int4*)(q + (size_t)row * K + k);
  const int4 a = qp[0], b = qp[1];
  u16x8 o;
  o[0] = f2bf(((float)a.x - zv) * sv);
  o[1] = f2bf(((float)a.y - zv) * sv);
  o[2] = f2bf(((float)a.z - zv) * sv);
  o[3] = f2bf(((float)a.w - zv) * sv);
  o[4] = f2bf(((float)b.x - zv) * sv);
  o[5] = f2bf(((float)b.y - zv) * sv);
  o[6] = f2bf(((float)b.z - zv) * sv);
  o[7] = f2bf(((float)b.w - zv) * sv);
  *reinterpret_cast<u16x8*>(w + (size_t)row * K + k) = o;
}

// ---------------- fp32 -> bf16 bulk convert (x)
__global__ __launch_bounds__(256)
void cvt_kernel(const float* __restrict__ in, u16* __restrict__ out) {
  const size_t i = ((size_t)blockIdx.x * 256 + threadIdx.x) << 3;
  const float4* p = (const float4*)(in + i);
  const float4 a = p[0], b = p[1];
  u16x8 o;
  o[0] = f2bf(a.x); o[1] = f2bf(a.y); o[2] = f2bf(a.z); o[3] = f2bf(a.w);
  o[4] = f2bf(b.x); o[5] = f2bf(b.y); o[6] = f2bf(b.z); o[7] = f2bf(b.w);
  *reinterpret_cast<u16x8*>(out + i) = o;
}

// ---------------- 256x256 8-phase GEMM v2: C[M,N] = A[M,K] * B[N,K]^T (bf16, K-major)
// 512 thr = 8 waves (2M x 4N); per-wave 128x64 out; BK=64; buf parity = K-tile parity.
// ks-split fragment sets (each set single-phase-live -> read-ahead costs 0 extra regs):
//   A1=af[0-3]ks0  A2=af[4-7]ks0  A3=af[0-3]ks1  A4=af[4-7]ks1  B1=bfr[0-3]ks0  B2=bfr[0-3]ks1
// Per tile N (buf p, stage tile N+1 into buf q):
//   ph1: rd B1,A1 (same-phase) + A2 (ahead) | stg A h0,h1 | BAR MFMA(A1*B1->acc[0-3]) BAR
//   ph2: rd A3,B2 (ahead)                   | stg B h0,h1 | BAR MFMA(A2*B1->acc[4-7]) BAR
//   ph3: rd A4 (ahead)                      |             | BAR MFMA(A3*B2->acc[0-3]) BAR
//   ph4: vmcnt(0) gate (stages 2 phases old)|             | BAR MFMA(A4*B2->acc[4-7]) BAR
// No explicit lgkmcnt: compiler emits exact counted waits per MFMA operand, so
// phase-ahead reads drain UNDER the current MFMA cluster (the whole point).
// Ledger: stage->read guarded by gate + 2 barriers; read->stage by operand
// consumption (compiler waits) before trailing barrier of ph4, stages issue after ph1's
// leading context. vmcnt(0) at ph4 drains exactly this tile's 8 stage loads.
template<bool RELU2>
__global__ __launch_bounds__(512, 2)
void gemm256(const u16* __restrict__ Ap, const u16* __restrict__ Bp,
             void* __restrict__ Cptr, int M, int N, int K) {
  __shared__ __align__(16) u16 As[2][256][64];
  __shared__ __align__(16) u16 Bs[2][256][64];
  const int tid = threadIdx.x;
  const int lane = tid & 63;
  const int wid = tid >> 6;
  const int wr = wid >> 2, wc = wid & 3;

  const int nbx = N >> 8;
  const int nwg = gridDim.x;
  int bid = blockIdx.x;
  bid = (bid & 7) * (nwg >> 3) + (bid >> 3);   // XCD swizzle (nwg % 8 == 0)
  const int m0 = (bid / nbx) << 8;
  const int n0 = (bid % nbx) << 8;

  const int srow = tid >> 3;        // staging row within 64-row sweep
  const int scol = tid & 7;         // staging 16B segment
  const int lr = lane & 15;
  const int lk = (lane >> 4) << 3;
  const int xorc = (lr & 7) << 3;   // read-side swizzle (row&7 == lr&7)

  f32x4 acc[8][4] = {};
  bf16x8 a1[4], a2[4], a3[4], a4[4], b1[4], b2[4];

  const int nk = K >> 6;

#define STG_A(bufi, h, kt) do { _Pragma("unroll") \
  for (int l_ = 0; l_ < 2; ++l_) { \
    const int r_ = (h) * 128 + l_ * 64 + srow; \
    gload_lds16(Ap + (size_t)(m0 + r_) * K + (size_t)((kt) << 6) + ((scol ^ (srow & 7)) << 3), \
                &As[bufi][r_][scol << 3]); } } while (0)
#define STG_B(bufi, h, kt) do { _Pragma("unroll") \
  for (int l_ = 0; l_ < 2; ++l_) { \
    const int r_ = (h) * 128 + l_ * 64 + srow; \
    gload_lds16(Bp + (size_t)(n0 + r_) * K + (size_t)((kt) << 6) + ((scol ^ (srow & 7)) << 3), \
                &Bs[bufi][r_][scol << 3]); } } while (0)
#define RD_A(bufi, ks, half, dst) do { _Pragma("unroll") \
  for (int i_ = 0; i_ < 4; ++i_) { \
    const int row_ = wr * 128 + ((half) * 4 + i_) * 16 + lr; \
    dst[i_] = *reinterpret_cast<const bf16x8*>(&As[bufi][row_][((ks) * 32 + lk) ^ xorc]); } } while (0)
#define RD_B(bufi, ks, dst) do { _Pragma("unroll") \
  for (int j_ = 0; j_ < 4; ++j_) { \
    const int row_ = wc * 64 + j_ * 16 + lr; \
    dst[j_] = *reinterpret_cast<const bf16x8*>(&Bs[bufi][row_][((ks) * 32 + lk) ^ xorc]); } } while (0)
#define MFMA16(ASET, BSET, I0) do { _Pragma("unroll") \
  for (int i_ = 0; i_ < 4; ++i_) { _Pragma("unroll") \
    for (int j_ = 0; j_ < 4; ++j_) \
      acc[(I0) + i_][j_] = __builtin_amdgcn_mfma_f32_16x16x32_bf16( \
        ASET[i_], BSET[j_], acc[(I0) + i_][j_], 0, 0, 0); } } while (0)
#define BAR() do { asm volatile("" ::: "memory"); __builtin_amdgcn_s_barrier(); \
  asm volatile("" ::: "memory"); } while (0)
#define VMGATE() asm volatile("s_waitcnt vmcnt(0)" ::: "memory")
#define TILE(p, q, ktn) do { \
  RD_B(p, 0, b1); RD_A(p, 0, 0, a1); RD_A(p, 0, 1, a2); \
  STG_A(q, 0, ktn); STG_A(q, 1, ktn); \
  BAR(); __builtin_amdgcn_s_setprio(1); MFMA16(a1, b1, 0); __builtin_amdgcn_s_setprio(0); BAR(); \
  RD_A(p, 1, 0, a3); RD_B(p, 1, b2); \
  STG_B(q, 0, ktn); STG_B(q, 1, ktn); \
  BAR(); __builtin_amdgcn_s_setprio(1); MFMA16(a2, b1, 4); __builtin_amdgcn_s_setprio(0); BAR(); \
  RD_A(p, 1, 1, a4); \
  BAR(); __builtin_amdgcn_s_setprio(1); MFMA16(a3, b2, 0); __builtin_amdgcn_s_setprio(0); BAR(); \
  VMGATE(); \
  BAR(); __builtin_amdgcn_s_setprio(1); MFMA16(a4, b2, 4); __builtin_amdgcn_s_setprio(0); BAR(); \
} while (0)

  // prologue: stage tile 0 into buf0, gate, barrier
  STG_A(0, 0, 0); STG_A(0, 1, 0);
  STG_B(0, 0, 0); STG_B(0, 1, 0);
  VMGATE();
  BAR();

  const int nit = nk >> 1;
  for (int it = 0; it < nit; ++it) {
    const int t1 = 2 * it + 1;
    int t2 = 2 * it + 2; if (t2 >= nk) t2 = 0;  // wrap: tail stage is a dummy
    TILE(0, 1, t1);
    TILE(1, 0, t2);
  }

  // epilogue: C/D layout col = lane&15, row = (lane>>4)*4 + reg  [m89-verified]
  const int crow = (lane >> 4) << 2;
  const int ccol = lane & 15;
#pragma unroll
  for (int i = 0; i < 8; ++i) {
#pragma unroll
    for (int j = 0; j < 4; ++j) {
#pragma unroll
      for (int q = 0; q < 4; ++q) {
        const int m = m0 + wr * 128 + i * 16 + crow + q;
        const int n = n0 + wc * 64 + j * 16 + ccol;
        const float v = acc[i][j][q];
        if constexpr (RELU2) {
          const float r = fmaxf(v, 0.f);
          ((u16*)Cptr)[(size_t)m * N + n] = f2bf(r * r);
        } else {
          ((float*)Cptr)[(size_t)m * N + n] = v;
        }
      }
    }
  }
#undef STG_A
#undef STG_B
#undef RD_A
#undef RD_B
#undef MFMA16
#undef BAR
#undef VMGATE
#undef TILE
}

extern "C" void kernel_launch(void* const* d_in, const int* in_sizes, int n_in,
                              void* d_out, int out_size, void* d_ws, size_t ws_size,
                              hipStream_t stream) {
  const float* x    = (const float*)d_in[0];
  const int*   q_up = (const int*)d_in[1];
  const float* s_up = (const float*)d_in[2];
  const int*   z_up = (const int*)d_in[3];
  const int*   q_dn = (const int*)d_in[4];
  const float* s_dn = (const float*)d_in[5];
  const int*   z_dn = (const int*)d_in[6];
  float* y = (float*)d_out;

  const int H = 4096, I = 14336;
  const int M = in_sizes[0] / H;  // 4096 tokens

  const size_t wbytes = (size_t)I * H * 2;   // 117.4 MB bf16 weight buffer (reused)
  const size_t abytes = (size_t)M * I * 2;   // 117.4 MB bf16 activations
  const size_t xbytes = (size_t)M * H * 2;   // 33.5 MB bf16 x
  u16* wbuf = (u16*)d_ws;
  u16* abuf = (u16*)((char*)d_ws + wbytes);
  u16* xbf  = (u16*)((char*)d_ws + wbytes + abytes);
  if (ws_size < wbytes + abytes + xbytes) return;  // insufficient scratch: fail cleanly

  // 1. dequant W_up [I, H] -> bf16
  dequant_kernel<<<dim3(H / 8 / 256, I), 256, 0, stream>>>(q_up, s_up, z_up, wbuf, H);
  // 1b. x -> bf16
  cvt_kernel<<<dim3((int)(((size_t)M * H) >> 11)), 256, 0, stream>>>(x, xbf);
  // 2. a = relu(x @ W_up^T)^2, bf16   (grid 896 % 8 == 0)
  gemm256<true><<<dim3((M / 256) * (I / 256)), 512, 0, stream>>>(xbf, wbuf, abuf, M, I, H);
  // 3. dequant W_down [H, I] -> bf16
  dequant_kernel<<<dim3(I / 8 / 256, H), 256, 0, stream>>>(q_dn, s_dn, z_dn, wbuf, I);
  // 4. y = a @ W_down^T, fp32   (grid 256 % 8 == 0)
  gemm256<false><<<dim3((M / 256) * (H / 256)), 512, 0, stream>>>(abuf, wbuf, y, M, H, I);
}